// Round 5
// baseline (244.507 us; speedup 1.0000x reference)
//
#include <hip/hip_runtime.h>
#include <hip/hip_bf16.h>
#include <stdint.h>

// Problem constants
#define NFEAT 4096   // IN_FEATURES == OUT_FEATURES
#define MROWS 1024   // batch
// K (top-k) = 41, ALPHA_LR = 0.01, NUM_DYKSTRA_ITER = 50

typedef __bf16 bf16x8 __attribute__((ext_vector_type(8)));
typedef float  f32x4  __attribute__((ext_vector_type(4)));

__device__ __forceinline__ unsigned short bf16_rne(float f) {
    unsigned int u = __float_as_uint(f);
    unsigned int r = (u + 0x7fffu + ((u >> 16) & 1u)) >> 16;
    return (unsigned short)r;
}

#define GLDS(src, dst) \
    __builtin_amdgcn_global_load_lds((__attribute__((address_space(1))) const void*)(src), \
                                     (__attribute__((address_space(3))) void*)(dst), 16, 0, 0)

// ---------------- Kernel 1: Dykstra soft top-k (1 block) ----------------
__global__ __launch_bounds__(256) void dykstra_kernel(const float* __restrict__ alpha,
                                                      float* __restrict__ g) {
    __shared__ float red[8];
    const int tid = threadIdx.x;
    float y[16], p[16], q[16], yp[16];
    #pragma unroll
    for (int j = 0; j < 16; ++j) {
        y[j] = alpha[tid + 256 * j] / 0.01f;   // y0 = x / l
        p[j] = 0.0f;
        q[j] = 0.0f;
    }
    for (int it = 0; it < 50; ++it) {
        float s = 0.0f;
        #pragma unroll
        for (int j = 0; j < 16; ++j) { yp[j] = y[j] + p[j]; s += yp[j]; }
        #pragma unroll
        for (int off = 32; off > 0; off >>= 1) s += __shfl_down(s, off, 64);
        const int half = (it & 1) * 4;          // WAR-safe double buffer
        if ((tid & 63) == 0) red[half + (tid >> 6)] = s;
        __syncthreads();
        const float S = (red[half] + red[half + 1]) + (red[half + 2] + red[half + 3]);
        const float shift = (S - 41.0f) / 4096.0f;  // (sum - k) / n
        #pragma unroll
        for (int j = 0; j < 16; ++j) {
            float y_hp = yp[j] - shift;
            p[j] = yp[j] - y_hp;            // NOT folded to 'shift' (fp semantics)
            float yq = y_hp + q[j];
            float yb = fminf(fmaxf(yq, 0.0f), 1.0f);
            q[j] = yq - yb;
            y[j] = yb;
        }
    }
    #pragma unroll
    for (int j = 0; j < 16; ++j) g[tid + 256 * j] = y[j];
}

// ---------------- Kernel 2: cvt x->bf16 + materialize W in bf16 -------------
// Each of 1024 blocks first converts its 16 KB slice of x, then builds a
// 256(r) x 64(c) tile of W[r,c] = g[(r-c)%n] * V[(r-c)%n, c].
// LDS band stride padded to 66 elems: write-phase anti-diagonal reads were
// 4-way bank-conflicted at stride 64 (drb step === 0 mod 32); at 66 they are
// <=2-way (free, m136).
__global__ __launch_bounds__(256) void build_w_kernel(const float* __restrict__ V,
                                                      const float* __restrict__ g,
                                                      const float* __restrict__ x,
                                                      unsigned short* __restrict__ xb,
                                                      unsigned short* __restrict__ Wb) {
    __shared__ unsigned short vb[319 * 66];   // ~42 KB bf16, already *g
    const int tid = threadIdx.x;
    const int bid = blockIdx.y * 64 + blockIdx.x;
    // --- cvt slice: 4096 floats per block ---
    {
        const size_t base = (size_t)bid * 4096 + (size_t)tid * 16;
        float4 a0 = *(const float4*)(x + base);
        float4 a1 = *(const float4*)(x + base + 4);
        float4 a2 = *(const float4*)(x + base + 8);
        float4 a3 = *(const float4*)(x + base + 12);
        uint4 s0, s1;
        s0.x = bf16_rne(a0.x) | ((unsigned)bf16_rne(a0.y) << 16);
        s0.y = bf16_rne(a0.z) | ((unsigned)bf16_rne(a0.w) << 16);
        s0.z = bf16_rne(a1.x) | ((unsigned)bf16_rne(a1.y) << 16);
        s0.w = bf16_rne(a1.z) | ((unsigned)bf16_rne(a1.w) << 16);
        s1.x = bf16_rne(a2.x) | ((unsigned)bf16_rne(a2.y) << 16);
        s1.y = bf16_rne(a2.z) | ((unsigned)bf16_rne(a2.w) << 16);
        s1.z = bf16_rne(a3.x) | ((unsigned)bf16_rne(a3.y) << 16);
        s1.w = bf16_rne(a3.z) | ((unsigned)bf16_rne(a3.w) << 16);
        *(uint4*)(xb + base)     = s0;
        *(uint4*)(xb + base + 8) = s1;
    }
    // --- band load: 319 rows x 16 float4, premultiplied by g ---
    const int c0 = blockIdx.x * 64;
    const int r0 = blockIdx.y * 256;
    const int i0 = (r0 - c0 - 63) & 4095;
    #pragma unroll
    for (int j = 0; j < 20; ++j) {
        int idx = tid + 256 * j;
        if (idx < 5104) {
            int t   = idx >> 4;
            int col = (idx & 15) << 2;
            int i   = (i0 + t) & 4095;
            float gv = g[i];
            float4 v = *(const float4*)(V + (size_t)i * NFEAT + c0 + col);
            uint2 pk;
            pk.x = bf16_rne(v.x * gv) | ((unsigned)bf16_rne(v.y * gv) << 16);
            pk.y = bf16_rne(v.z * gv) | ((unsigned)bf16_rne(v.w * gv) << 16);
            *(uint2*)(vb + t * 66 + col) = pk;
        }
    }
    __syncthreads();
    const int dcp = tid & 15;       // col group: cols 4*dcp .. 4*dcp+3
    const int drb = tid >> 4;       // 16 rows per pass
    #pragma unroll
    for (int j = 0; j < 16; ++j) {
        int dr = drb + 16 * j;
        int c  = dcp * 4;
        int tb = dr - c + 63;       // in [3, 318]
        unsigned short w0 = vb[tb * 66 + c];
        unsigned short w1 = vb[(tb - 1) * 66 + c + 1];
        unsigned short w2 = vb[(tb - 2) * 66 + c + 2];
        unsigned short w3 = vb[(tb - 3) * 66 + c + 3];
        uint2 st;
        st.x = w0 | ((unsigned)w1 << 16);
        st.y = w2 | ((unsigned)w3 << 16);
        *(uint2*)(Wb + (size_t)(r0 + dr) * NFEAT + c0 + c) = st;
    }
}

// ---------------- Kernel 3: split-K GEMM, 256x256x32, atomic epilogue -------
// v6 = v4's verified 4-phase counted-vmcnt pipeline (62us, MfmaUtil 21%),
// with the split-K reduce FUSED AWAY: all z-slices unsafeAtomicAdd into out
// (HW global_atomic_add_f32; out zeroed by hipMemsetAsync at launch head,
// stream-ordered). Kills the reduce kernel + 48MB Cp write + 64MB Cp read +
// 16MB out re-read + one launch gap. fp32 add order across z is arbitrary:
// ~1ulp-of-partial difference vs sequential reduce (absmax margin 3x).
// Atomic pattern: per wave-instr 4 rows x 16 consecutive dwords -> 4 full
// 64B lines, HW-coalescable.
// Staged-bytes model (v5 lesson): staged = M*K*(N/Tn) + N*K*(M/Tm); 256^2
// = 256MB (v5's 128x256 was 384MB -> regressed). Keep 256^2.
// Pipeline (v4, race-proved in r2 post-mortem):
//   P0: read af0-3,b0,b1; stage A(kt+3); BAR; lgkm0; MFMA ni{0,1}
//   P1: read b2,b3;       stage B(kt+3); BAR; lgkm0; MFMA ni{2,3}
//   P2: read b4,b5,b6,b7;               BAR; lgkm0; MFMA ni{4,5}
//   P3: vmcnt(8);                       BAR;        MFMA ni{6,7}
// WAR: b6,b7 read early in P2, drained by P2's lgkm0 -> no LDS reads in
// flight across P3's barrier (the only barrier a stage into buf[kt&3] can
// follow). RAW: at P3's vmcnt(8), outstanding = tiles kt+1..kt+3 = 12 loads;
// retire tile kt+1's 4; never 0 in steady state. Tail: vmcnt(4)/(0).
__global__ __launch_bounds__(512, 2) void gemm_kernel(const unsigned short* __restrict__ A,
                                                      const unsigned short* __restrict__ B,
                                                      float* __restrict__ out) {
    __shared__ unsigned short As[4][8192];   // 16 KB per buf
    __shared__ unsigned short Bs[4][8192];
    const int tid  = threadIdx.x;
    const int lane = tid & 63;
    const int w    = tid >> 6;       // 0..7
    const int wm   = w & 3;          // m strip (64 rows)
    const int wn   = w >> 2;         // n strip (128 cols)
    const int m0   = blockIdx.y * 256;
    const int n0   = blockIdx.x * 256;
    const int kbase = blockIdx.z * 1024;   // 32 iters x BK=32

    f32x4 acc[4][8];
    #pragma unroll
    for (int i = 0; i < 4; ++i)
        #pragma unroll
        for (int j = 0; j < 8; ++j)
            acc[i][j] = (f32x4){0.f, 0.f, 0.f, 0.f};

    // staging: wave w covers kg = w&3, row-quarters rq = (w>>2)*2 + {0,1}
    const int kgS = w & 3;
    const int rqB = (w >> 2) * 2;
    const unsigned short* aS = A + (size_t)(m0 + rqB * 64 + lane) * NFEAT + kbase + kgS * 8;
    const unsigned short* bS = B + (size_t)(n0 + rqB * 64 + lane) * NFEAT + kbase + kgS * 8;
    const int dOff = kgS * 2048 + rqB * 512;   // elems; +512 for second rq

    const int kg4 = lane >> 4;
    const int lm  = lane & 15;
    const int aOff = kg4 * 2048 + (wm * 64 + lm) * 8;
    const int bOff = kg4 * 2048 + (wn * 128 + lm) * 8;

    // full-tile stage (prologue only)
    auto stage = [&](int kt) {
        const int ko = kt * 32;
        const int nb = kt & 3;
        GLDS(aS + ko,              As[nb] + dOff);
        GLDS(aS + ko + 64 * NFEAT, As[nb] + dOff + 512);
        GLDS(bS + ko,              Bs[nb] + dOff);
        GLDS(bS + ko + 64 * NFEAT, Bs[nb] + dOff + 512);
    };

#define MMA8(B0, B1, NI0, NI1)                                                              \
    __builtin_amdgcn_s_setprio(1);                                                          \
    acc[0][NI0] = __builtin_amdgcn_mfma_f32_16x16x32_bf16(af0, B0, acc[0][NI0], 0, 0, 0);   \
    acc[1][NI0] = __builtin_amdgcn_mfma_f32_16x16x32_bf16(af1, B0, acc[1][NI0], 0, 0, 0);   \
    acc[2][NI0] = __builtin_amdgcn_mfma_f32_16x16x32_bf16(af2, B0, acc[2][NI0], 0, 0, 0);   \
    acc[3][NI0] = __builtin_amdgcn_mfma_f32_16x16x32_bf16(af3, B0, acc[3][NI0], 0, 0, 0);   \
    acc[0][NI1] = __builtin_amdgcn_mfma_f32_16x16x32_bf16(af0, B1, acc[0][NI1], 0, 0, 0);   \
    acc[1][NI1] = __builtin_amdgcn_mfma_f32_16x16x32_bf16(af1, B1, acc[1][NI1], 0, 0, 0);   \
    acc[2][NI1] = __builtin_amdgcn_mfma_f32_16x16x32_bf16(af2, B1, acc[2][NI1], 0, 0, 0);   \
    acc[3][NI1] = __builtin_amdgcn_mfma_f32_16x16x32_bf16(af3, B1, acc[3][NI1], 0, 0, 0);   \
    __builtin_amdgcn_s_setprio(0)

#define KSTEP(KT, STAGE_EN, VMSTMT) do {                                                    \
    const int _kt = (KT);                                                                   \
    const unsigned short* aRd = As[_kt & 3] + aOff;                                         \
    const unsigned short* bRd = Bs[_kt & 3] + bOff;                                         \
    bf16x8 af0, af1, af2, af3, p0, p1, p2, p3, p4, p5, p6, p7;                              \
    af0 = *(const bf16x8*)(aRd);        af1 = *(const bf16x8*)(aRd + 128);                  \
    af2 = *(const bf16x8*)(aRd + 256);  af3 = *(const bf16x8*)(aRd + 384);                  \
    p0  = *(const bf16x8*)(bRd);        p1  = *(const bf16x8*)(bRd + 128);                  \
    if (STAGE_EN) {                                                                         \
        const int _ko = (_kt + 3) * 32;  const int _nb = (_kt + 3) & 3;                     \
        GLDS(aS + _ko,              As[_nb] + dOff);                                        \
        GLDS(aS + _ko + 64 * NFEAT, As[_nb] + dOff + 512);                                  \
    }                                                                                       \
    __builtin_amdgcn_s_barrier();                                                           \
    asm volatile("s_waitcnt lgkmcnt(0)" ::: "memory");                                      \
    __builtin_amdgcn_sched_barrier(0);                                                      \
    MMA8(p0, p1, 0, 1);                                                                     \
    p2 = *(const bf16x8*)(bRd + 256);   p3 = *(const bf16x8*)(bRd + 384);                   \
    if (STAGE_EN) {                                                                         \
        const int _ko = (_kt + 3) * 32;  const int _nb = (_kt + 3) & 3;                     \
        GLDS(bS + _ko,              Bs[_nb] + dOff);                                        \
        GLDS(bS + _ko + 64 * NFEAT, Bs[_nb] + dOff + 512);                                  \
    }                                                                                       \
    __builtin_amdgcn_s_barrier();                                                           \
    asm volatile("s_waitcnt lgkmcnt(0)" ::: "memory");                                      \
    __builtin_amdgcn_sched_barrier(0);                                                      \
    MMA8(p2, p3, 2, 3);                                                                     \
    p4 = *(const bf16x8*)(bRd + 512);   p5 = *(const bf16x8*)(bRd + 640);                   \
    p6 = *(const bf16x8*)(bRd + 768);   p7 = *(const bf16x8*)(bRd + 896);                   \
    __builtin_amdgcn_s_barrier();                                                           \
    asm volatile("s_waitcnt lgkmcnt(0)" ::: "memory");                                      \
    __builtin_amdgcn_sched_barrier(0);                                                      \
    MMA8(p4, p5, 4, 5);                                                                     \
    VMSTMT;                                                                                 \
    __builtin_amdgcn_s_barrier();                                                           \
    __builtin_amdgcn_sched_barrier(0);                                                      \
    MMA8(p6, p7, 6, 7);                                                                     \
} while (0)

    stage(0); stage(1); stage(2);          // prologue: 12 loads in flight
    asm volatile("s_waitcnt vmcnt(8)" ::: "memory");   // tile 0 landed
    __builtin_amdgcn_s_barrier();                       // published to all waves
    #pragma unroll 1
    for (int kt = 0; kt < 29; ++kt) {
        KSTEP(kt, 1, asm volatile("s_waitcnt vmcnt(8)" ::: "memory"));
    }
    KSTEP(29, 0, asm volatile("s_waitcnt vmcnt(4)" ::: "memory"));
    KSTEP(30, 0, asm volatile("s_waitcnt vmcnt(0)" ::: "memory"));
    KSTEP(31, 0, (void)0);

    // epilogue: accumulate into out via HW fp32 atomics (out pre-zeroed).
    // C/D layout: col = lane&15, row = (lane>>4)*4 + reg  (m89-verified)
    const int crow = m0 + wm * 64 + (lane >> 4) * 4;
    const int ccol = n0 + wn * 128 + lm;
    #pragma unroll
    for (int mi = 0; mi < 4; ++mi)
        #pragma unroll
        for (int ni = 0; ni < 8; ++ni) {
            float* cp = out + (size_t)(crow + mi * 16) * NFEAT + ccol + ni * 16;
            #pragma unroll
            for (int r = 0; r < 4; ++r)
                unsafeAtomicAdd(cp + (size_t)r * NFEAT, acc[mi][ni][r]);
        }
}

extern "C" void kernel_launch(void* const* d_in, const int* in_sizes, int n_in,
                              void* d_out, int out_size, void* d_ws, size_t ws_size,
                              hipStream_t stream) {
    const float* x     = (const float*)d_in[0];   // (1024, 4096) fp32
    const float* V     = (const float*)d_in[1];   // (4096, 4096) fp32
    const float* alpha = (const float*)d_in[2];   // (4096,) fp32
    float* out = (float*)d_out;                   // (1024, 4096) fp32

    char* ws = (char*)d_ws;
    const size_t xb_off = 16384;
    const size_t wb_off = xb_off + (size_t)MROWS * NFEAT * 2;   // + 8 MB
    float* g           = (float*)ws;
    unsigned short* xb = (unsigned short*)(ws + xb_off);
    unsigned short* Wb = (unsigned short*)(ws + wb_off);

    // zero out for the atomic split-K epilogue (stream-ordered, capture-safe)
    hipMemsetAsync(out, 0, (size_t)MROWS * NFEAT * sizeof(float), stream);
    hipLaunchKernelGGL(dykstra_kernel, dim3(1),        dim3(256), 0, stream, alpha, g);
    hipLaunchKernelGGL(build_w_kernel, dim3(64, 16),   dim3(256), 0, stream, V, g, x, xb, Wb);
    hipLaunchKernelGGL(gemm_kernel,    dim3(16, 4, 4), dim3(512), 0, stream, xb, Wb, out);
}

// Round 6
// 204.123 us; speedup vs baseline: 1.1978x; 1.1978x over previous
//
#include <hip/hip_runtime.h>
#include <hip/hip_bf16.h>
#include <stdint.h>

// Problem constants
#define NFEAT 4096   // IN_FEATURES == OUT_FEATURES
#define MROWS 1024   // batch
// K (top-k) = 41, ALPHA_LR = 0.01, NUM_DYKSTRA_ITER = 50

typedef __bf16 bf16x8 __attribute__((ext_vector_type(8)));
typedef float  f32x4  __attribute__((ext_vector_type(4)));

__device__ __forceinline__ unsigned short bf16_rne(float f) {
    unsigned int u = __float_as_uint(f);
    unsigned int r = (u + 0x7fffu + ((u >> 16) & 1u)) >> 16;
    return (unsigned short)r;
}

#define GLDS(src, dst) \
    __builtin_amdgcn_global_load_lds((__attribute__((address_space(1))) const void*)(src), \
                                     (__attribute__((address_space(3))) void*)(dst), 16, 0, 0)

// ------- Kernel 1: Dykstra soft top-k (block 0) + x->bf16 cvt (blocks 1..1024)
// The 50-iteration Dykstra loop is serial and barrier-bound on ONE block;
// previously 255/256 CUs sat idle while it ran, and the cvt then ran serially
// inside build_w. Running cvt in blocks 1..1024 hides it entirely under the
// Dykstra block (independent work, no ordering needed: build_w consumes g,
// gemm consumes xb, both launched after).
__global__ __launch_bounds__(256) void dykstra_cvt_kernel(const float* __restrict__ alpha,
                                                          float* __restrict__ g,
                                                          const float* __restrict__ x,
                                                          unsigned short* __restrict__ xb) {
    __shared__ float red[8];
    const int tid = threadIdx.x;
    if (blockIdx.x != 0) {
        // --- cvt slice: 4096 floats per block ---
        const int bid = blockIdx.x - 1;
        const size_t base = (size_t)bid * 4096 + (size_t)tid * 16;
        float4 a0 = *(const float4*)(x + base);
        float4 a1 = *(const float4*)(x + base + 4);
        float4 a2 = *(const float4*)(x + base + 8);
        float4 a3 = *(const float4*)(x + base + 12);
        uint4 s0, s1;
        s0.x = bf16_rne(a0.x) | ((unsigned)bf16_rne(a0.y) << 16);
        s0.y = bf16_rne(a0.z) | ((unsigned)bf16_rne(a0.w) << 16);
        s0.z = bf16_rne(a1.x) | ((unsigned)bf16_rne(a1.y) << 16);
        s0.w = bf16_rne(a1.z) | ((unsigned)bf16_rne(a1.w) << 16);
        s1.x = bf16_rne(a2.x) | ((unsigned)bf16_rne(a2.y) << 16);
        s1.y = bf16_rne(a2.z) | ((unsigned)bf16_rne(a2.w) << 16);
        s1.z = bf16_rne(a3.x) | ((unsigned)bf16_rne(a3.y) << 16);
        s1.w = bf16_rne(a3.z) | ((unsigned)bf16_rne(a3.w) << 16);
        *(uint4*)(xb + base)     = s0;
        *(uint4*)(xb + base + 8) = s1;
        return;
    }
    // --- block 0: Dykstra ---
    float y[16], p[16], q[16], yp[16];
    #pragma unroll
    for (int j = 0; j < 16; ++j) {
        y[j] = alpha[tid + 256 * j] / 0.01f;   // y0 = x / l
        p[j] = 0.0f;
        q[j] = 0.0f;
    }
    for (int it = 0; it < 50; ++it) {
        float s = 0.0f;
        #pragma unroll
        for (int j = 0; j < 16; ++j) { yp[j] = y[j] + p[j]; s += yp[j]; }
        #pragma unroll
        for (int off = 32; off > 0; off >>= 1) s += __shfl_down(s, off, 64);
        const int half = (it & 1) * 4;          // WAR-safe double buffer
        if ((tid & 63) == 0) red[half + (tid >> 6)] = s;
        __syncthreads();
        const float S = (red[half] + red[half + 1]) + (red[half + 2] + red[half + 3]);
        const float shift = (S - 41.0f) / 4096.0f;  // (sum - k) / n
        #pragma unroll
        for (int j = 0; j < 16; ++j) {
            float y_hp = yp[j] - shift;
            p[j] = yp[j] - y_hp;            // NOT folded to 'shift' (fp semantics)
            float yq = y_hp + q[j];
            float yb = fminf(fmaxf(yq, 0.0f), 1.0f);
            q[j] = yq - yb;
            y[j] = yb;
        }
    }
    #pragma unroll
    for (int j = 0; j < 16; ++j) g[tid + 256 * j] = y[j];
}

// ---------------- Kernel 2: materialize W in bf16 ----------------
// Each of 1024 blocks builds a 256(r) x 64(c) tile of
// W[r,c] = g[(r-c)%n] * V[(r-c)%n, c].  (cvt moved to kernel 1.)
// LDS band stride padded to 66 elems: write-phase anti-diagonal reads were
// 4-way bank-conflicted at stride 64; at 66 they are <=2-way (free, m136).
__global__ __launch_bounds__(256) void build_w_kernel(const float* __restrict__ V,
                                                      const float* __restrict__ g,
                                                      unsigned short* __restrict__ Wb) {
    __shared__ unsigned short vb[319 * 66];   // ~42 KB bf16, already *g
    const int tid = threadIdx.x;
    // --- band load: 319 rows x 16 float4, premultiplied by g ---
    const int c0 = blockIdx.x * 64;
    const int r0 = blockIdx.y * 256;
    const int i0 = (r0 - c0 - 63) & 4095;
    #pragma unroll
    for (int j = 0; j < 20; ++j) {
        int idx = tid + 256 * j;
        if (idx < 5104) {
            int t   = idx >> 4;
            int col = (idx & 15) << 2;
            int i   = (i0 + t) & 4095;
            float gv = g[i];
            float4 v = *(const float4*)(V + (size_t)i * NFEAT + c0 + col);
            uint2 pk;
            pk.x = bf16_rne(v.x * gv) | ((unsigned)bf16_rne(v.y * gv) << 16);
            pk.y = bf16_rne(v.z * gv) | ((unsigned)bf16_rne(v.w * gv) << 16);
            *(uint2*)(vb + t * 66 + col) = pk;
        }
    }
    __syncthreads();
    const int dcp = tid & 15;       // col group: cols 4*dcp .. 4*dcp+3
    const int drb = tid >> 4;       // 16 rows per pass
    #pragma unroll
    for (int j = 0; j < 16; ++j) {
        int dr = drb + 16 * j;
        int c  = dcp * 4;
        int tb = dr - c + 63;       // in [3, 318]
        unsigned short w0 = vb[tb * 66 + c];
        unsigned short w1 = vb[(tb - 1) * 66 + c + 1];
        unsigned short w2 = vb[(tb - 2) * 66 + c + 2];
        unsigned short w3 = vb[(tb - 3) * 66 + c + 3];
        uint2 st;
        st.x = w0 | ((unsigned)w1 << 16);
        st.y = w2 | ((unsigned)w3 << 16);
        *(uint2*)(Wb + (size_t)(r0 + dr) * NFEAT + c0 + c) = st;
    }
}

// ---------------- Kernel 3: split-K GEMM, 256x256x32 ----------------
// v7 = v4's counted-vmcnt pipeline with the 4 phases MERGED to 2 (16 MFMA
// per phase, m198-density). Per K-step:
//   PhA: all 12 ds_read (af0-3, b0-7); stage A+B(kt+3); BAR; lgkm0; MFMA ni0-3
//   PhB: vmcnt(8);                                      BAR;        MFMA ni4-7
// Race proof (rigorous, v2's lesson):
//  WAR: stage(kt+3) -> buf[(kt-1)&3]. ALL reads of buf[(kt-1)&3] were issued
//    in PhA(kt-1) and drained by PhA(kt-1)'s lgkmcnt(0), which precedes
//    PhB(kt-1)'s barrier in program order. A wave can only issue stage(kt+3)
//    after passing PhB(kt-1)'s barrier => every wave's reads already drained.
//    PhB's MFMAs are register-only: nothing in flight across PhB's barrier.
//  RAW: at PhB(kt)'s vmcnt(8): outstanding = tiles {kt+1,kt+2,kt+3} = 12
//    loads; retire 4 oldest = tile kt+1; PhB barrier publishes cross-wave.
//    Reads of tile kt+1 happen in PhA(kt+1), strictly after. Never drains to
//    0 in steady state. Tail: vmcnt(4), vmcnt(0), none.
// 512 threads = 8 waves (4m x 2n), wave = 64m x 128n, acc 4x8 f32x4.
// LDS [buf4][kg(4)][row(256)][8] A and B = 128 KB, kg-outer layout ->
// 0 bank conflicts measured (no swizzle needed). Grid (16,4,4), 1 block/CU.
__global__ __launch_bounds__(512, 2) void gemm_kernel(const unsigned short* __restrict__ A,
                                                      const unsigned short* __restrict__ B,
                                                      float* __restrict__ C0,
                                                      float* __restrict__ Cp) {
    __shared__ unsigned short As[4][8192];   // 16 KB per buf
    __shared__ unsigned short Bs[4][8192];
    const int tid  = threadIdx.x;
    const int lane = tid & 63;
    const int w    = tid >> 6;       // 0..7
    const int wm   = w & 3;          // m strip (64 rows)
    const int wn   = w >> 2;         // n strip (128 cols)
    const int m0   = blockIdx.y * 256;
    const int n0   = blockIdx.x * 256;
    const int kbase = blockIdx.z * 1024;   // 32 iters x BK=32

    f32x4 acc[4][8];
    #pragma unroll
    for (int i = 0; i < 4; ++i)
        #pragma unroll
        for (int j = 0; j < 8; ++j)
            acc[i][j] = (f32x4){0.f, 0.f, 0.f, 0.f};

    // staging: wave w covers kg = w&3, row-quarters rq = (w>>2)*2 + {0,1}
    const int kgS = w & 3;
    const int rqB = (w >> 2) * 2;
    const unsigned short* aS = A + (size_t)(m0 + rqB * 64 + lane) * NFEAT + kbase + kgS * 8;
    const unsigned short* bS = B + (size_t)(n0 + rqB * 64 + lane) * NFEAT + kbase + kgS * 8;
    const int dOff = kgS * 2048 + rqB * 512;   // elems; +512 for second rq

    const int kg4 = lane >> 4;
    const int lm  = lane & 15;
    const int aOff = kg4 * 2048 + (wm * 64 + lm) * 8;
    const int bOff = kg4 * 2048 + (wn * 128 + lm) * 8;

    // full-tile stage
    auto stage = [&](int kt) {
        const int ko = kt * 32;
        const int nb = kt & 3;
        GLDS(aS + ko,              As[nb] + dOff);
        GLDS(aS + ko + 64 * NFEAT, As[nb] + dOff + 512);
        GLDS(bS + ko,              Bs[nb] + dOff);
        GLDS(bS + ko + 64 * NFEAT, Bs[nb] + dOff + 512);
    };

#define MMA8(B0, B1, NI0, NI1)                                                              \
    acc[0][NI0] = __builtin_amdgcn_mfma_f32_16x16x32_bf16(af0, B0, acc[0][NI0], 0, 0, 0);   \
    acc[1][NI0] = __builtin_amdgcn_mfma_f32_16x16x32_bf16(af1, B0, acc[1][NI0], 0, 0, 0);   \
    acc[2][NI0] = __builtin_amdgcn_mfma_f32_16x16x32_bf16(af2, B0, acc[2][NI0], 0, 0, 0);   \
    acc[3][NI0] = __builtin_amdgcn_mfma_f32_16x16x32_bf16(af3, B0, acc[3][NI0], 0, 0, 0);   \
    acc[0][NI1] = __builtin_amdgcn_mfma_f32_16x16x32_bf16(af0, B1, acc[0][NI1], 0, 0, 0);   \
    acc[1][NI1] = __builtin_amdgcn_mfma_f32_16x16x32_bf16(af1, B1, acc[1][NI1], 0, 0, 0);   \
    acc[2][NI1] = __builtin_amdgcn_mfma_f32_16x16x32_bf16(af2, B1, acc[2][NI1], 0, 0, 0);   \
    acc[3][NI1] = __builtin_amdgcn_mfma_f32_16x16x32_bf16(af3, B1, acc[3][NI1], 0, 0, 0)

#define KSTEP(KT, STAGE_EN, VMSTMT) do {                                                    \
    const int _kt = (KT);                                                                   \
    const unsigned short* aRd = As[_kt & 3] + aOff;                                         \
    const unsigned short* bRd = Bs[_kt & 3] + bOff;                                         \
    bf16x8 af0, af1, af2, af3, p0, p1, p2, p3, p4, p5, p6, p7;                              \
    af0 = *(const bf16x8*)(aRd);        af1 = *(const bf16x8*)(aRd + 128);                  \
    af2 = *(const bf16x8*)(aRd + 256);  af3 = *(const bf16x8*)(aRd + 384);                  \
    p0  = *(const bf16x8*)(bRd);        p1  = *(const bf16x8*)(bRd + 128);                  \
    p2  = *(const bf16x8*)(bRd + 256);  p3  = *(const bf16x8*)(bRd + 384);                  \
    p4  = *(const bf16x8*)(bRd + 512);  p5  = *(const bf16x8*)(bRd + 640);                  \
    p6  = *(const bf16x8*)(bRd + 768);  p7  = *(const bf16x8*)(bRd + 896);                  \
    if (STAGE_EN) {                                                                         \
        const int _ko = (_kt + 3) * 32;  const int _nb = (_kt + 3) & 3;                     \
        GLDS(aS + _ko,              As[_nb] + dOff);                                        \
        GLDS(aS + _ko + 64 * NFEAT, As[_nb] + dOff + 512);                                  \
        GLDS(bS + _ko,              Bs[_nb] + dOff);                                        \
        GLDS(bS + _ko + 64 * NFEAT, Bs[_nb] + dOff + 512);                                  \
    }                                                                                       \
    __builtin_amdgcn_s_barrier();                                                           \
    asm volatile("s_waitcnt lgkmcnt(0)" ::: "memory");                                      \
    __builtin_amdgcn_sched_barrier(0);                                                      \
    __builtin_amdgcn_s_setprio(1);                                                          \
    MMA8(p0, p1, 0, 1);                                                                     \
    MMA8(p2, p3, 2, 3);                                                                     \
    __builtin_amdgcn_s_setprio(0);                                                          \
    VMSTMT;                                                                                 \
    __builtin_amdgcn_s_barrier();                                                           \
    __builtin_amdgcn_sched_barrier(0);                                                      \
    __builtin_amdgcn_s_setprio(1);                                                          \
    MMA8(p4, p5, 4, 5);                                                                     \
    MMA8(p6, p7, 6, 7);                                                                     \
    __builtin_amdgcn_s_setprio(0);                                                          \
} while (0)

    stage(0); stage(1); stage(2);          // prologue: 12 loads in flight
    asm volatile("s_waitcnt vmcnt(8)" ::: "memory");   // tile 0 landed
    __builtin_amdgcn_s_barrier();                       // published to all waves
    #pragma unroll 1
    for (int kt = 0; kt < 29; ++kt) {
        KSTEP(kt, 1, asm volatile("s_waitcnt vmcnt(8)" ::: "memory"));
    }
    KSTEP(29, 0, asm volatile("s_waitcnt vmcnt(4)" ::: "memory"));
    KSTEP(30, 0, asm volatile("s_waitcnt vmcnt(0)" ::: "memory"));
    KSTEP(31, 0, (void)0);

    float* Cz = (blockIdx.z == 0) ? C0 : (Cp + (size_t)(blockIdx.z - 1) * MROWS * NFEAT);
    // C/D layout: col = lane&15, row = (lane>>4)*4 + reg  (m89-verified)
    const int crow = m0 + wm * 64 + (lane >> 4) * 4;
    const int ccol = n0 + wn * 128 + lm;
    #pragma unroll
    for (int mi = 0; mi < 4; ++mi)
        #pragma unroll
        for (int ni = 0; ni < 8; ++ni) {
            float* cp = Cz + (size_t)(crow + mi * 16) * NFEAT + ccol + ni * 16;
            #pragma unroll
            for (int r = 0; r < 4; ++r)
                cp[(size_t)r * NFEAT] = acc[mi][ni][r];
        }
}

// ---------------- Kernel 4: split-K reduce: out += sum of partials ----------
__global__ __launch_bounds__(256) void reduce_kernel(float* __restrict__ out,
                                                     const float* __restrict__ Cp) {
    const size_t i = (size_t)(blockIdx.x * 256 + threadIdx.x) * 4;
    float4 a = *(const float4*)(out + i);
    #pragma unroll
    for (int s = 0; s < 3; ++s) {
        float4 b = *(const float4*)(Cp + (size_t)s * MROWS * NFEAT + i);
        a.x += b.x; a.y += b.y; a.z += b.z; a.w += b.w;
    }
    *(float4*)(out + i) = a;
}

extern "C" void kernel_launch(void* const* d_in, const int* in_sizes, int n_in,
                              void* d_out, int out_size, void* d_ws, size_t ws_size,
                              hipStream_t stream) {
    const float* x     = (const float*)d_in[0];   // (1024, 4096) fp32
    const float* V     = (const float*)d_in[1];   // (4096, 4096) fp32
    const float* alpha = (const float*)d_in[2];   // (4096,) fp32
    float* out = (float*)d_out;                   // (1024, 4096) fp32

    char* ws = (char*)d_ws;
    const size_t xb_off = 16384;
    const size_t wb_off = xb_off + (size_t)MROWS * NFEAT * 2;   // + 8 MB
    const size_t cp_off = wb_off + (size_t)NFEAT * NFEAT * 2;   // +32 MB
    float* g           = (float*)ws;
    unsigned short* xb = (unsigned short*)(ws + xb_off);
    unsigned short* Wb = (unsigned short*)(ws + wb_off);
    float* Cp          = (float*)(ws + cp_off);                 // 48 MB (S=4)

    hipLaunchKernelGGL(dykstra_cvt_kernel, dim3(1025),   dim3(256), 0, stream, alpha, g, x, xb);
    hipLaunchKernelGGL(build_w_kernel,     dim3(64, 16), dim3(256), 0, stream, V, g, Wb);
    hipLaunchKernelGGL(gemm_kernel,        dim3(16, 4, 4), dim3(512), 0, stream, xb, Wb, out, Cp);
    hipLaunchKernelGGL(reduce_kernel,      dim3(MROWS * NFEAT / (256 * 4)), dim3(256), 0, stream,
                       out, Cp);
}